// Round 9
// baseline (114.650 us; speedup 1.0000x reference)
//
#include <hip/hip_runtime.h>

#define N_NODES 50000
#define D 128
#define NC 128                 // edge chunks (= countA/scatterC grid)
#define SCANB 196              // scanAB blocks (196*256 = 50176 >= N)

typedef short bf16x8 __attribute__((ext_vector_type(8)));
typedef float f32x4 __attribute__((ext_vector_type(4)));
typedef float f32x2 __attribute__((ext_vector_type(2)));

__device__ __forceinline__ ushort f2bf(float f) {
    uint u = __float_as_uint(f);
    u += 0x7FFF + ((u >> 16) & 1);     // round-to-nearest-even
    return (ushort)(u >> 16);
}

// unpack 16 fp8 (int4) and accumulate into a[0..16)
__device__ __forceinline__ void addrow_fp8(int4 q, float* a) {
    f32x2 p;
    p = __builtin_amdgcn_cvt_pk_f32_fp8(q.x, false); a[0]  += p.x; a[1]  += p.y;
    p = __builtin_amdgcn_cvt_pk_f32_fp8(q.x, true);  a[2]  += p.x; a[3]  += p.y;
    p = __builtin_amdgcn_cvt_pk_f32_fp8(q.y, false); a[4]  += p.x; a[5]  += p.y;
    p = __builtin_amdgcn_cvt_pk_f32_fp8(q.y, true);  a[6]  += p.x; a[7]  += p.y;
    p = __builtin_amdgcn_cvt_pk_f32_fp8(q.z, false); a[8]  += p.x; a[9]  += p.y;
    p = __builtin_amdgcn_cvt_pk_f32_fp8(q.z, true);  a[10] += p.x; a[11] += p.y;
    p = __builtin_amdgcn_cvt_pk_f32_fp8(q.w, false); a[12] += p.x; a[13] += p.y;
    p = __builtin_amdgcn_cvt_pk_f32_fp8(q.w, true);  a[14] += p.x; a[15] += p.y;
}

// ====== convert: x->bf16 + x->fp8 + fragment-major B build (pure BW) ========
__global__ __launch_bounds__(256) void convert_kernel(const float* __restrict__ x,
                                                      const float* __restrict__ Wl,
                                                      const float* __restrict__ Wr,
                                                      ushort* __restrict__ x_bf,
                                                      int* __restrict__ x_fp8,
                                                      ushort* __restrict__ Btf) {
    const int i = blockIdx.x * 256 + threadIdx.x;
    if (i < (N_NODES * D) / 4) {
        float4 v = ((const float4*)x)[i];
        ushort4 o;
        o.x = f2bf(v.x); o.y = f2bf(v.y); o.z = f2bf(v.z); o.w = f2bf(v.w);
        ((ushort4*)x_bf)[i] = o;
        int p = __builtin_amdgcn_cvt_pk_fp8_f32(v.x, v.y, 0, false);
        p = __builtin_amdgcn_cvt_pk_fp8_f32(v.z, v.w, p, true);
        x_fp8[i] = p;
    }
    // fragment-major B: Btf[((ks*8+nf)*64 + l)*8 + j] = W[k][col]
    if (i < 32768) {
        int j  = i & 7;
        int l  = (i >> 3) & 63;
        int nf = (i >> 9) & 7;
        int ks = (i >> 12) & 7;
        int lr = l & 15, kb = l >> 4;
        int col  = nf * 16 + lr;
        int kloc = (ks & 3) * 32 + kb * 8 + j;
        const float* W = (ks < 4) ? Wl : Wr;
        Btf[i] = f2bf(W[kloc * D + col]);
    }
}

// ====== pass A: per-chunk LDS histogram (packed 2x ushort per uint) =========
__global__ __launch_bounds__(512) void countA_kernel(const int* __restrict__ dst,
                                                     ushort* __restrict__ partial,
                                                     int E, int chunk) {
    __shared__ uint cnt[N_NODES / 2];     // 25000 uints = 100 KB
    const int t = threadIdx.x;
    const int b = blockIdx.x;
    for (int k = t; k < N_NODES / 2; k += 512) cnt[k] = 0;
    __syncthreads();
    const int e0 = b * chunk;
    const int e1 = min(E, e0 + chunk);
    for (int e = e0 + t; e < e1; e += 512) {
        int d = dst[e];
        atomicAdd(&cnt[d >> 1], 1u << ((d & 1) << 4));
    }
    __syncthreads();
    uint* pu = (uint*)(partial + (size_t)b * N_NODES);
    for (int k = t; k < N_NODES / 2; k += 512) pu[k] = cnt[k];
}

// ====== pass B: per-node chunk-prefix + block-LOCAL exclusive scan ==========
// offsets written WITHOUT cross-block base; consumers add base from blocksums.
__global__ __launch_bounds__(256) void scanAB_kernel(const ushort* __restrict__ partial,
                                                     ushort* __restrict__ cumbase,
                                                     int* __restrict__ offsets,
                                                     int* __restrict__ blocksums) {
    __shared__ int wsums[4];
    __shared__ int wbase[4];
    const int t = threadIdx.x;
    const int lane = t & 63;
    const int wid = t >> 6;
    const int n = blockIdx.x * 256 + t;

    int s = 0;
    if (n < N_NODES) {
        #pragma unroll 4
        for (int c = 0; c < NC; ++c) {
            int v = (int)partial[(size_t)c * N_NODES + n];
            cumbase[(size_t)c * N_NODES + n] = (ushort)s;
            s += v;
        }
    }
    int sc = s;
    #pragma unroll
    for (int off = 1; off < 64; off <<= 1) {
        int u = __shfl_up(sc, off);
        if (lane >= off) sc += u;
    }
    if (lane == 63) wsums[wid] = sc;
    __syncthreads();
    if (t == 0) {
        int c = 0;
        #pragma unroll
        for (int w = 0; w < 4; ++w) { int tmp = wsums[w]; wbase[w] = c; c += tmp; }
        blocksums[blockIdx.x] = c;
    }
    __syncthreads();
    if (n < N_NODES) offsets[n] = wbase[wid] + sc - s;
}

// ====== pass C: scatter into CSR (LDS ranks + inline base scan) =============
__global__ __launch_bounds__(512) void scatterC_kernel(const int* __restrict__ src,
                                                       const int* __restrict__ dst,
                                                       const int* __restrict__ offsets,
                                                       const int* __restrict__ blocksums,
                                                       const ushort* __restrict__ cumbase,
                                                       ushort* __restrict__ sorted_src,
                                                       int E, int chunk) {
    __shared__ uint cnt[N_NODES / 2];     // 100 KB
    __shared__ int base[SCANB];
    const int t = threadIdx.x;
    const int b = blockIdx.x;
    for (int k = t; k < N_NODES / 2; k += 512) cnt[k] = 0;
    if (t < SCANB) base[t] = blocksums[t];
    __syncthreads();
    if (t == 0) {                          // serial exclusive scan of 196 entries
        int run = 0;
        for (int k = 0; k < SCANB; ++k) { int v = base[k]; base[k] = run; run += v; }
    }
    __syncthreads();
    const ushort* cb = cumbase + (size_t)b * N_NODES;
    const int e0 = b * chunk;
    const int e1 = min(E, e0 + chunk);
    for (int e = e0 + t; e < e1; e += 512) {
        int d = dst[e];
        uint prev = atomicAdd(&cnt[d >> 1], 1u << ((d & 1) << 4));
        int lrank = (int)((prev >> ((d & 1) << 4)) & 0xFFFFu);
        int pos = offsets[d] + base[d >> 8] + (int)cb[d] + lrank;
        sorted_src[pos] = (ushort)src[e];
    }
}

// ====== fused aggregate(fp8 gather) + MFMA GEMM + bias + relu ===============
// 64 nodes/block, 256 threads. Aggregation: 4 lanes/node, 32 f32 acc each,
// writes bf16 agg tile to LDS. GEMM: 4 waves x (16 rows x 128 cols),
// A ks<4 from LDS, ks>=4 from x_bf (global), B from Btf (L2-hot).
__global__ __launch_bounds__(256) void aggemm2_kernel(const int* __restrict__ x_fp8,
                                                      const ushort* __restrict__ x_bf,
                                                      const ushort* __restrict__ sorted_src,
                                                      const int* __restrict__ offsets,
                                                      const int* __restrict__ blocksums,
                                                      const ushort* __restrict__ Btf,
                                                      const float* __restrict__ bias,
                                                      float* __restrict__ out, int E) {
    __shared__ ushort aggT[64][136];      // 17,408 B
    __shared__ int base[SCANB];
    const int t = threadIdx.x;
    const int n0 = blockIdx.x * 64;

    if (t < SCANB) base[t] = blocksums[t];
    __syncthreads();
    if (t == 0) {
        int run = 0;
        for (int k = 0; k < SCANB; ++k) { int v = base[k]; base[k] = run; run += v; }
    }
    __syncthreads();

    // ---------------- phase 1: aggregation ----------------
    {
        const int g = t >> 2;              // node slot 0..63
        const int j = t & 3;               // quarter: int4 idx 2j,2j+1 (cols j*32..+31)
        const int node = n0 + g;
        float a[32];
        #pragma unroll
        for (int k = 0; k < 32; ++k) a[k] = 0.0f;

        if (node < N_NODES) {
            const int s = offsets[node] + base[node >> 8];
            const int np = node + 1;
            const int e = (np < N_NODES) ? (offsets[np] + base[np >> 8]) : E;
            const int4* xq = (const int4*)x_fp8;   // row = 8 int4s
            int p = s;
            for (; p + 4 <= e; p += 4) {
                int s0 = sorted_src[p + 0];
                int s1 = sorted_src[p + 1];
                int s2 = sorted_src[p + 2];
                int s3 = sorted_src[p + 3];
                int4 qa0 = xq[s0 * 8 + 2 * j], qb0 = xq[s0 * 8 + 2 * j + 1];
                int4 qa1 = xq[s1 * 8 + 2 * j], qb1 = xq[s1 * 8 + 2 * j + 1];
                int4 qa2 = xq[s2 * 8 + 2 * j], qb2 = xq[s2 * 8 + 2 * j + 1];
                int4 qa3 = xq[s3 * 8 + 2 * j], qb3 = xq[s3 * 8 + 2 * j + 1];
                addrow_fp8(qa0, a); addrow_fp8(qb0, a + 16);
                addrow_fp8(qa1, a); addrow_fp8(qb1, a + 16);
                addrow_fp8(qa2, a); addrow_fp8(qb2, a + 16);
                addrow_fp8(qa3, a); addrow_fp8(qb3, a + 16);
            }
            for (; p < e; ++p) {
                int s0 = sorted_src[p];
                int4 qa = xq[s0 * 8 + 2 * j], qb = xq[s0 * 8 + 2 * j + 1];
                addrow_fp8(qa, a); addrow_fp8(qb, a + 16);
            }
            const int dcnt = e - s;
            const float scale = (dcnt > 0) ? (1.0f / (float)dcnt) : 0.0f;
            #pragma unroll
            for (int k = 0; k < 32; ++k) a[k] *= scale;
        }
        ushort tmp[32];
        #pragma unroll
        for (int k = 0; k < 32; ++k) tmp[k] = f2bf(a[k]);
        #pragma unroll
        for (int q = 0; q < 4; ++q)
            *(int4*)&aggT[g][j * 32 + q * 8] = ((int4*)tmp)[q];
    }
    __syncthreads();

    // ---------------- phase 2: MFMA GEMM ----------------
    const int w = t >> 6;
    const int l = t & 63;
    const int lr = l & 15;
    const int kb = l >> 4;
    const int rloc = w * 16 + lr;          // 0..63
    int r = n0 + rloc; if (r >= N_NODES) r = N_NODES - 1;

    f32x4 acc[8] = {};
    #pragma unroll
    for (int ks = 0; ks < 8; ++ks) {
        bf16x8 af = (ks < 4)
            ? *(bf16x8*)&aggT[rloc][ks * 32 + kb * 8]
            : *(const bf16x8*)&x_bf[r * D + (ks - 4) * 32 + kb * 8];
        const ushort* bp = Btf + (size_t)(ks * 8 * 64 + l) * 8;
        #pragma unroll
        for (int nf = 0; nf < 8; ++nf) {
            bf16x8 bfr = *(const bf16x8*)&bp[nf * 64 * 8];
            acc[nf] = __builtin_amdgcn_mfma_f32_16x16x32_bf16(af, bfr, acc[nf], 0, 0, 0);
        }
    }

    // C/D layout: col = lane&15, row = (lane>>4)*4 + i
    #pragma unroll
    for (int nf = 0; nf < 8; ++nf) {
        const int col = nf * 16 + lr;
        const float bb = bias[col];
        #pragma unroll
        for (int i = 0; i < 4; ++i) {
            int row = n0 + w * 16 + kb * 4 + i;
            if (row < N_NODES)
                out[row * D + col] = fmaxf(acc[nf][i] + bb, 0.0f);
        }
    }
}

// ============================================================================
extern "C" void kernel_launch(void* const* d_in, const int* in_sizes, int n_in,
                              void* d_out, int out_size, void* d_ws, size_t ws_size,
                              hipStream_t stream) {
    const float* x  = (const float*)d_in[0];
    const int*   ei = (const int*)d_in[1];
    const float* Wl = (const float*)d_in[2];
    const float* Wr = (const float*)d_in[3];
    const float* b  = (const float*)d_in[4];
    float* out = (float*)d_out;

    const int E = in_sizes[1] / 2;
    const int* src = ei;
    const int* dst = ei + E;
    const int chunk = (E + NC - 1) / NC;

    // workspace layout (16B-aligned sections)
    char* wsp = (char*)d_ws;
    int*    offsets   = (int*)(wsp + 0);               // 50176 ints (local scan)
    int*    blocksums = (int*)(wsp + 200704);          // 256 ints
    ushort* sorted    = (ushort*)(wsp + 201728);       // 800016 ushorts
    ushort* partial   = (ushort*)(wsp + 1801760);      // 128*50000 ushorts (12.8MB)
    ushort* cumbase   = (ushort*)(wsp + 14601760);     // 128*50000 ushorts (12.8MB)
    ushort* x_bf      = (ushort*)(wsp + 27401760);     // 6,400,000 ushorts
    int*    x_fp8     = (int*)(wsp + 40201760);        // 1,600,000 ints
    ushort* Btf       = (ushort*)(wsp + 46601760);     // 32768 ushorts
    // total = 46,667,296 bytes

    convert_kernel<<<(N_NODES * D / 4 + 255) / 256, 256, 0, stream>>>(
        x, Wl, Wr, x_bf, x_fp8, Btf);
    countA_kernel<<<NC, 512, 0, stream>>>(dst, partial, E, chunk);
    scanAB_kernel<<<SCANB, 256, 0, stream>>>(partial, cumbase, offsets, blocksums);
    scatterC_kernel<<<NC, 512, 0, stream>>>(src, dst, offsets, blocksums, cumbase,
                                            sorted, E, chunk);
    aggemm2_kernel<<<(N_NODES + 63) / 64, 256, 0, stream>>>(
        x_fp8, x_bf, sorted, offsets, blocksums, Btf, b, out, E);
}